// Round 1
// baseline (795.070 us; speedup 1.0000x reference)
//
#include <hip/hip_runtime.h>
#include <hip/hip_bf16.h>

typedef __attribute__((ext_vector_type(4))) float floatx4;
typedef __attribute__((ext_vector_type(8))) short shortx8;

#define MFMA(a, b, c) __builtin_amdgcn_mfma_f32_16x16x32_bf16(a, b, c, 0, 0, 0)

static constexpr int MTOT = 16384;   // B*N rows
static constexpr int NSEQ = 4096;
static constexpr int CD = 256;
static constexpr float SCALE = 0.125f;  // D^-0.5

__device__ __forceinline__ unsigned short f2bf(float f) {
  unsigned int u = __float_as_uint(f);
  u += 0x7fffu + ((u >> 16) & 1u);   // RNE
  return (unsigned short)(u >> 16);
}

__device__ __forceinline__ shortx8 ld8(const unsigned short* p) {
  return *reinterpret_cast<const shortx8*>(p);
}

// ---------------- fp32 -> bf16 cast ----------------
__global__ __launch_bounds__(256) void cast_kernel(const float* __restrict__ src,
                                                   unsigned short* __restrict__ dst, int n) {
  int i = (blockIdx.x * 256 + threadIdx.x) * 4;
  if (i + 3 < n) {
    float4 v = *reinterpret_cast<const float4*>(src + i);
    ushort4 o;
    o.x = f2bf(v.x); o.y = f2bf(v.y); o.z = f2bf(v.z); o.w = f2bf(v.w);
    *reinterpret_cast<ushort4*>(dst + i) = o;
  }
}

// ---------------- fused QKV projections: y = X @ W^T + b (bias applied here) ----------------
// j: 0:Xf*Wqf->Q1  1:Xs*Wks->K1  2:Xs*Wvs->V1  3:Xs*Wqs->Q2  4:Xf*Wkf->K2  5:Xf*Wvf->V2
struct BiasPtrs { const float* p[6]; };

__global__ __launch_bounds__(256) void qkv_gemm(const unsigned short* __restrict__ Xf,
                                                const unsigned short* __restrict__ Xs,
                                                const unsigned short* __restrict__ W6,
                                                BiasPtrs bias6,
                                                unsigned short* __restrict__ Yout) {
  const int j = blockIdx.y;
  const unsigned short* X = ((14 >> j) & 1) ? Xs : Xf;   // j=1,2,3 use Xs
  const unsigned short* W = W6 + j * 65536;
  const float* bias = bias6.p[j];
  unsigned short* Y = Yout + (size_t)j * MTOT * CD;

  const int wave = threadIdx.x >> 6, lane = threadIdx.x & 63;
  const int col = lane & 15, quad = lane >> 4;
  const int m0 = blockIdx.x * 32;
  const int o0 = wave * 64;

  floatx4 acc[2][4];
  for (int mt = 0; mt < 2; ++mt)
    for (int f = 0; f < 4; ++f) acc[mt][f] = floatx4{0.f, 0.f, 0.f, 0.f};

  for (int k0 = 0; k0 < CD; k0 += 32) {
    shortx8 a[2], bb[4];
    for (int mt = 0; mt < 2; ++mt)
      a[mt] = ld8(X + (size_t)(m0 + mt * 16 + col) * CD + k0 + quad * 8);
    for (int f = 0; f < 4; ++f)
      bb[f] = ld8(W + (size_t)(o0 + f * 16 + col) * CD + k0 + quad * 8);
    for (int mt = 0; mt < 2; ++mt)
      for (int f = 0; f < 4; ++f)
        acc[mt][f] = MFMA(a[mt], bb[f], acc[mt][f]);
  }
  for (int mt = 0; mt < 2; ++mt)
    for (int f = 0; f < 4; ++f) {
      const int oc = o0 + f * 16 + col;
      const float bv = bias[oc];
      for (int r = 0; r < 4; ++r)
        Y[(size_t)(m0 + mt * 16 + quad * 4 + r) * CD + oc] = f2bf(acc[mt][f][r] + bv);
    }
}

// ---------------- V transpose: per (dir,b,h) V[n][d] -> Vt[d][n] ----------------
__global__ __launch_bounds__(256) void vtrans(const unsigned short* __restrict__ qkv,
                                              unsigned short* __restrict__ Vt) {
  __shared__ unsigned short tile[64][65];
  const int pb = blockIdx.y;                     // dir*16 + b*4 + h
  const int dir = pb >> 4, b = (pb >> 2) & 3, h = pb & 3;
  const size_t SZ = (size_t)MTOT * CD;
  const unsigned short* V = qkv + (size_t)dir * 3 * SZ + 2 * SZ;
  const int n0 = blockIdx.x * 64;
  const int t = threadIdx.x;
  const int dcol = t & 63, nrow = t >> 6;
  for (int nn = 0; nn < 64; nn += 4)
    tile[nn + nrow][dcol] = V[(size_t)(b * NSEQ + n0 + nn + nrow) * CD + h * 64 + dcol];
  __syncthreads();
  const int ncol = t & 63, drow = t >> 6;
  unsigned short* dst = Vt + (size_t)pb * 64 * NSEQ;
  for (int dd = 0; dd < 64; dd += 4)
    dst[(size_t)(dd + drow) * NSEQ + n0 + ncol] = tile[ncol][dd + drow];
}

// ---------------- flash attention: 1 wave = 32 q-rows, K-tile = 32 ----------------
__global__ __launch_bounds__(256) void attn_kernel(const unsigned short* __restrict__ qkv,
                                                   const unsigned short* __restrict__ Vt,
                                                   unsigned short* __restrict__ Oout) {
  const size_t SZ = (size_t)MTOT * CD;
  const int pb = blockIdx.y;
  const int dir = pb >> 4, b = (pb >> 2) & 3, h = pb & 3;
  const unsigned short* Q = qkv + (size_t)dir * 3 * SZ;
  const unsigned short* K = Q + SZ;
  const unsigned short* VT = Vt + (size_t)pb * 64 * NSEQ;
  unsigned short* O = Oout + (size_t)dir * SZ;

  const int wave = threadIdx.x >> 6, lane = threadIdx.x & 63;
  const int col = lane & 15, quad = lane >> 4;
  const int rowbase = b * NSEQ;
  const int cb = h * 64;
  const int q0 = blockIdx.x * 128 + wave * 32;

  shortx8 qf[2][2];
  for (int mt = 0; mt < 2; ++mt)
    for (int c = 0; c < 2; ++c)
      qf[mt][c] = ld8(Q + (size_t)(rowbase + q0 + mt * 16 + col) * CD + cb + c * 32 + quad * 8);

  floatx4 oacc[2][4];
  for (int mt = 0; mt < 2; ++mt)
    for (int d = 0; d < 4; ++d) oacc[mt][d] = floatx4{0.f, 0.f, 0.f, 0.f};
  float mst[2] = {-1e30f, -1e30f}, lst[2] = {0.f, 0.f};

  // permuted K row so that two S^T tiles concatenate into the k=quad*8+j A-fragment
  const int gp = 8 * (col >> 2) + (col & 3);

  for (int kt = 0; kt < NSEQ; kt += 32) {
    shortx8 kf[2][2];
    for (int t = 0; t < 2; ++t)
      for (int c = 0; c < 2; ++c)
        kf[t][c] = ld8(K + (size_t)(rowbase + kt + gp + 4 * t) * CD + cb + c * 32 + quad * 8);
    shortx8 vf[4];
    for (int db = 0; db < 4; ++db)
      vf[db] = ld8(VT + (size_t)(db * 16 + col) * NSEQ + kt + quad * 8);

    for (int mt = 0; mt < 2; ++mt) {
      floatx4 z = floatx4{0.f, 0.f, 0.f, 0.f};
      floatx4 st0 = MFMA(kf[0][0], qf[mt][0], z);
      st0 = MFMA(kf[0][1], qf[mt][1], st0);
      floatx4 st1 = MFMA(kf[1][0], qf[mt][0], z);
      st1 = MFMA(kf[1][1], qf[mt][1], st1);
      // lane holds S[q=col][kc=8*quad + i] for i in 0..7 (t0: i<4, t1: i>=4)
      float s[8];
      for (int r = 0; r < 4; ++r) { s[r] = st0[r] * SCALE; s[4 + r] = st1[r] * SCALE; }
      float mx = s[0];
      for (int i = 1; i < 8; ++i) mx = fmaxf(mx, s[i]);
      mx = fmaxf(mx, __shfl_xor(mx, 16));
      mx = fmaxf(mx, __shfl_xor(mx, 32));
      const float mnew = fmaxf(mst[mt], mx);
      const float al = __expf(mst[mt] - mnew);
      float p[8], sm = 0.f;
      for (int i = 0; i < 8; ++i) { p[i] = __expf(s[i] - mnew); sm += p[i]; }
      sm += __shfl_xor(sm, 16);
      sm += __shfl_xor(sm, 32);
      lst[mt] = lst[mt] * al + sm;
      mst[mt] = mnew;
      shortx8 pf;
      for (int i = 0; i < 8; ++i) pf[i] = (short)f2bf(p[i]);
      float alr[4];
      for (int r = 0; r < 4; ++r) alr[r] = __shfl(al, quad * 4 + r);
      for (int db = 0; db < 4; ++db) {
        floatx4 o = oacc[mt][db];
        for (int r = 0; r < 4; ++r) o[r] *= alr[r];
        oacc[mt][db] = MFMA(pf, vf[db], o);
      }
    }
  }
  for (int mt = 0; mt < 2; ++mt) {
    float lr[4];
    for (int r = 0; r < 4; ++r) lr[r] = 1.0f / __shfl(lst[mt], quad * 4 + r);
    for (int db = 0; db < 4; ++db)
      for (int r = 0; r < 4; ++r)
        O[(size_t)(rowbase + q0 + mt * 16 + quad * 4 + r) * CD + cb + db * 16 + col] =
            f2bf(oacc[mt][db][r] * lr[r]);
  }
}

// ---------------- final projection over concat [O1|O2] (K=512) + fused LayerNorm ----------------
__global__ __launch_bounds__(256) void final_ln(const unsigned short* __restrict__ O1,
                                                const unsigned short* __restrict__ O2,
                                                const unsigned short* __restrict__ Wp,
                                                const float* __restrict__ bp,
                                                const float* __restrict__ gamma,
                                                const float* __restrict__ beta,
                                                float* __restrict__ out) {
  __shared__ float ssum[4][32], ssq[4][32];
  const int wave = threadIdx.x >> 6, lane = threadIdx.x & 63;
  const int col = lane & 15, quad = lane >> 4;
  const int m0 = blockIdx.x * 32;
  const int o0 = wave * 64;

  floatx4 acc[2][4];
  for (int mt = 0; mt < 2; ++mt)
    for (int f = 0; f < 4; ++f) acc[mt][f] = floatx4{0.f, 0.f, 0.f, 0.f};

  for (int kk = 0; kk < 16; ++kk) {
    const unsigned short* src = (kk < 8) ? O1 : O2;
    const int k0 = (kk & 7) * 32;
    shortx8 a[2], bb[4];
    for (int mt = 0; mt < 2; ++mt)
      a[mt] = ld8(src + (size_t)(m0 + mt * 16 + col) * CD + k0 + quad * 8);
    for (int f = 0; f < 4; ++f)
      bb[f] = ld8(Wp + (size_t)(o0 + f * 16 + col) * 512 + kk * 32 + quad * 8);
    for (int mt = 0; mt < 2; ++mt)
      for (int f = 0; f < 4; ++f)
        acc[mt][f] = MFMA(a[mt], bb[f], acc[mt][f]);
  }

  float vals[2][4][4];
  for (int mt = 0; mt < 2; ++mt)
    for (int f = 0; f < 4; ++f) {
      const float bv = bp[o0 + f * 16 + col];
      for (int r = 0; r < 4; ++r) vals[mt][f][r] = acc[mt][f][r] + bv;
    }

  for (int mt = 0; mt < 2; ++mt)
    for (int r = 0; r < 4; ++r) {
      float s = 0.f, q = 0.f;
      for (int f = 0; f < 4; ++f) { float v = vals[mt][f][r]; s += v; q += v * v; }
      for (int d = 1; d < 16; d <<= 1) { s += __shfl_xor(s, d); q += __shfl_xor(q, d); }
      if (col == 0) {
        ssum[wave][mt * 16 + quad * 4 + r] = s;
        ssq[wave][mt * 16 + quad * 4 + r] = q;
      }
    }
  __syncthreads();
  for (int mt = 0; mt < 2; ++mt)
    for (int r = 0; r < 4; ++r) {
      const int rl = mt * 16 + quad * 4 + r;
      const float S = ssum[0][rl] + ssum[1][rl] + ssum[2][rl] + ssum[3][rl];
      const float Qs = ssq[0][rl] + ssq[1][rl] + ssq[2][rl] + ssq[3][rl];
      const float mean = S * (1.0f / 256.0f);
      const float var = Qs * (1.0f / 256.0f) - mean * mean;
      const float rs = rsqrtf(var + 1e-5f);
      for (int f = 0; f < 4; ++f) {
        const int oc = o0 + f * 16 + col;
        out[(size_t)(m0 + rl) * CD + oc] = (vals[mt][f][r] - mean) * rs * gamma[oc] + beta[oc];
      }
    }
}

extern "C" void kernel_launch(void* const* d_in, const int* in_sizes, int n_in,
                              void* d_out, int out_size, void* d_ws, size_t ws_size,
                              hipStream_t stream) {
  const float* f_freq = (const float*)d_in[0];
  const float* f_spat = (const float*)d_in[1];
  const float* Wqf = (const float*)d_in[2];  const float* bqf = (const float*)d_in[3];
  const float* Wks = (const float*)d_in[4];  const float* bks = (const float*)d_in[5];
  const float* Wvs = (const float*)d_in[6];  const float* bvs = (const float*)d_in[7];
  const float* Wqs = (const float*)d_in[8];  const float* bqs = (const float*)d_in[9];
  const float* Wkf = (const float*)d_in[10]; const float* bkf = (const float*)d_in[11];
  const float* Wvf = (const float*)d_in[12]; const float* bvf = (const float*)d_in[13];
  const float* Wp  = (const float*)d_in[14]; const float* bp  = (const float*)d_in[15];
  const float* gamma = (const float*)d_in[16];
  const float* beta  = (const float*)d_in[17];
  float* out = (float*)d_out;

  const size_t SZ = (size_t)MTOT * CD;
  unsigned short* Xf  = (unsigned short*)d_ws;      // SZ elems (later reused as Vt)
  unsigned short* Xs  = Xf + SZ;                    // SZ
  unsigned short* W6  = Xs + SZ;                    // 6*65536
  unsigned short* WpB = W6 + 6 * 65536;             // 131072
  unsigned short* QKV = WpB + 131072;               // 6*SZ: Q1 K1 V1 Q2 K2 V2
  unsigned short* O1  = QKV + 6 * SZ;               // SZ
  unsigned short* O2  = O1 + SZ;                    // SZ
  unsigned short* Vt  = Xf;                         // alias: Xf/Xs dead after qkv_gemm

  cast_kernel<<<4096, 256, 0, stream>>>(f_freq, Xf, (int)SZ);
  cast_kernel<<<4096, 256, 0, stream>>>(f_spat, Xs, (int)SZ);
  cast_kernel<<<64, 256, 0, stream>>>(Wqf, W6 + 0 * 65536, 65536);
  cast_kernel<<<64, 256, 0, stream>>>(Wks, W6 + 1 * 65536, 65536);
  cast_kernel<<<64, 256, 0, stream>>>(Wvs, W6 + 2 * 65536, 65536);
  cast_kernel<<<64, 256, 0, stream>>>(Wqs, W6 + 3 * 65536, 65536);
  cast_kernel<<<64, 256, 0, stream>>>(Wkf, W6 + 4 * 65536, 65536);
  cast_kernel<<<64, 256, 0, stream>>>(Wvf, W6 + 5 * 65536, 65536);
  cast_kernel<<<128, 256, 0, stream>>>(Wp, WpB, 131072);

  BiasPtrs bias6 = {{bqf, bks, bvs, bqs, bkf, bvf}};
  qkv_gemm<<<dim3(512, 6), 256, 0, stream>>>(Xf, Xs, W6, bias6, QKV);

  vtrans<<<dim3(64, 32), 256, 0, stream>>>(QKV, Vt);

  attn_kernel<<<dim3(32, 32), 256, 0, stream>>>(QKV, Vt, O1);

  final_ln<<<512, 256, 0, stream>>>(O1, O2, WpB, bp, gamma, beta, out);
}